// Round 7
// baseline (227.672 us; speedup 1.0000x reference)
//
#include <hip/hip_runtime.h>
#include <hip/hip_bf16.h>

using uint32   = unsigned int;
using ushort_t = unsigned short;
using short8   = __attribute__((ext_vector_type(8))) short;
using uint4v   = __attribute__((ext_vector_type(4))) uint32;
using float4v  = __attribute__((ext_vector_type(4))) float;
using floatx16 = __attribute__((ext_vector_type(16))) float;

#define M_DIM 32
#define K_DIM 8192
#define N_DIM 28672
#define QROW  (N_DIM/8)   /* 3584 dwords per qweight k-row */
#define KSPLIT 16
#define BN    128         /* narrower block: finer residency quantum */
#define NB    (N_DIM/BN)  /* 224 n-blocks */
#define CH    128         /* k per chunk == QGS */
#define NCH   4           /* chunks per block (K_DIM / KSPLIT / CH) */
#define TCOLS (BN/8)      /* 16 dword-columns of T */
#define TSTRIDE 132       /* T column stride in dwords (128 + 4 pad) */

__device__ ushort_t g_xr2[M_DIM * K_DIM]; // rotated x, k-octet-major MFMA-A order
__device__ float    g_S[64 * M_DIM];      // per-group row sums of bf16(xr)

__device__ __forceinline__ float bf2f(ushort_t u){
  unsigned int v = ((unsigned int)u) << 16;
  return __builtin_bit_cast(float, v);
}
__device__ __forceinline__ ushort_t f2bf(float f){
  return __builtin_bit_cast(ushort_t, __float2bfloat16(f)); // RNE
}

// T4 barrier: LDS-visibility only. No vmcnt drain. Memory-clobber asm on
// both sides pins LDS-op code motion (rule #18).
#define LDS_BARRIER() do {                                   \
  asm volatile("s_waitcnt lgkmcnt(0)" ::: "memory");         \
  __builtin_amdgcn_s_barrier();                              \
  asm volatile("" ::: "memory");                             \
} while (0)

// ------------- prep: rotation + group sums, and bias broadcast ---------
// blocks [0,512): one 64-lane unit per (m,g) rotation.
// blocks [512,960): out[m][n] = bias[n] for 8 m-rows each.
__global__ __launch_bounds__(256) void prep_kernel(
    const float* __restrict__ x, const float* __restrict__ theta,
    const int* __restrict__ pairs, const float* __restrict__ cs,
    const float* __restrict__ bias, float* __restrict__ out)
{
  if (blockIdx.x >= 512){
    const int b  = blockIdx.x - 512;
    const int n  = (b % (N_DIM/256))*256 + threadIdx.x;
    const int m0 = (b / (N_DIM/256))*8;
    const float bv = bias[n];
    #pragma unroll
    for (int m = 0; m < 8; ++m) out[(size_t)(m0+m)*N_DIM + n] = bv;
    return;
  }
  __shared__ float xb[4][128];
  const int u    = threadIdx.x >> 6;
  const int lane = threadIdx.x & 63;
  const int id   = blockIdx.x * 4 + u;   // 0..2047 = m*64+g
  const int m    = id >> 6;
  const int g    = id & 63;
  const float* xp = x + m*K_DIM + g*128;
  int   ip[8], jp[8];
  float cv[8], sv[8];
  #pragma unroll
  for (int k = 0; k < 8; ++k){
    ip[k] = pairs[k*128 + 2*lane];
    jp[k] = pairs[k*128 + 2*lane + 1];
    const float th = theta[k*(K_DIM/2) + g*64 + lane];
    cv[k] = cosf(th); sv[k] = sinf(th);
  }
  xb[u][lane]    = xp[lane];
  xb[u][lane+64] = xp[lane+64];
  #pragma unroll
  for (int k = 0; k < 8; ++k){
    __syncthreads();
    const float xi = xb[u][ip[k]], xj = xb[u][jp[k]];
    xb[u][ip[k]] = cv[k]*xi - sv[k]*xj;
    xb[u][jp[k]] = sv[k]*xi + cv[k]*xj;
  }
  __syncthreads();
  const int base = g*128;
  const int k0 = base + lane, k1 = base + lane + 64;
  const ushort_t b0 = f2bf(xb[u][lane]    * cs[k0]);
  const ushort_t b1 = f2bf(xb[u][lane+64] * cs[k1]);
  g_xr2[(((size_t)(k0>>3))*32 + m)*8 + (k0&7)] = b0;
  g_xr2[(((size_t)(k1>>3))*32 + m)*8 + (k1&7)] = b1;
  float sum = bf2f(b0) + bf2f(b1);
  #pragma unroll
  for (int d = 32; d > 0; d >>= 1) sum += __shfl_xor(sum, d, 64);
  if (lane == 0) g_S[g*M_DIM + m] = sum;
}

// ---- GEMM: 256-thread blocks, BN=128 — fine-grained residency ----
// Same per-wave work as r4/r6 (32 cols, full accT, 8 MFMA/chunk). Half
// the LDS (16.9 KB -> up to 8 blocks/CU), half the waves per barrier (4),
// 2x the independent blocks per CU (grid 3584). Isolates latency-hiding:
// occupancy ceiling rises 12 -> 32 waves/CU.
__global__ __launch_bounds__(256, 4) void gemm_kernel(
    const uint32* __restrict__ qw, const uint32* __restrict__ qz,
    const float* __restrict__ scales, float* __restrict__ out)
{
  __shared__ uint32 T[2][TCOLS*TSTRIDE];    // 2 x 8.4 KB transposed B chunk
  const int bid  = blockIdx.x;
  const int ks   = bid & (KSPLIT-1);
  const int nb   = bid >> 4;
  const int tid  = threadIdx.x;
  const int w    = tid >> 6;                // 0..3
  const int lane = tid & 63;
  const int l31  = lane & 31;
  const int koct = lane >> 5;
  const int n0   = nb * BN;
  const int n    = n0 + w*32 + l31;
  const uint32 sh = (uint32)((l31 & 7)*4);
  const int col  = w*4 + (l31 >> 3);        // T column 0..15 for this lane
  const int k0   = ks * (NCH*CH);           // 512*ks

  // B global-load mapping: per chunk the panel is 128 rows x 16 dwords =
  // 8 KB = 256 threads x dwordx4 x 2. Lanes 0..3 cover 64 contiguous bytes
  // of one k-row (coalesced 64B segments).
  const int brow = tid >> 2;                // 0..63
  const int bcq  = tid & 3;                 // 0..3
  const uint32* bbase = qw + (size_t)(k0 + brow)*QROW + (n0>>3) + bcq*4;
  const ushort_t* abase = g_xr2 + (size_t)k0*32;

  // ---- prelude: issue all B loads for this block (8 x dwordx4) ----
  uint4v bv0[NCH], bv1[NCH];
  #pragma unroll
  for (int c = 0; c < NCH; ++c){
    const uint32* bb = bbase + (size_t)c*CH*QROW;
    bv0[c] = *(const uint4v*)(bb);
    bv1[c] = *(const uint4v*)(bb + (size_t)64*QROW);
  }
  // per-chunk scalars (coalesced)
  float  sc[NCH];
  uint32 zc[NCH];
  #pragma unroll
  for (int c = 0; c < NCH; ++c){
    sc[c] = scales[(size_t)(ks*NCH + c)*N_DIM + n];
    zc[c] = qz[(size_t)(ks*NCH + c)*QROW + (n>>3)];
  }

  float accT[16];
  #pragma unroll
  for (int r = 0; r < 16; ++r) accT[r] = 0.f;

  // write T[0]; rotation mj=(j+bcq)&3 spreads write banks (<=3-way, minor)
  #pragma unroll
  for (int j = 0; j < 4; ++j){
    const int mj = (j + bcq) & 3;
    T[0][(bcq*4 + mj)*TSTRIDE + brow]      = bv0[0][mj];
    T[0][(bcq*4 + mj)*TSTRIDE + brow + 64] = bv1[0][mj];
  }
  LDS_BARRIER();                            // T[0] visible

  #pragma unroll
  for (int c = 0; c < NCH; ++c){
    const int cb = c & 1, nx = cb ^ 1;
    // next chunk's T from regs (loads long since issued)
    if (c + 1 < NCH){
      #pragma unroll
      for (int j = 0; j < 4; ++j){
        const int mj = (j + bcq) & 3;
        T[nx][(bcq*4 + mj)*TSTRIDE + brow]      = bv0[c+1][mj];
        T[nx][(bcq*4 + mj)*TSTRIDE + brow + 64] = bv1[c+1][mj];
      }
    }

    const ushort_t* ab = abase + (size_t)c*CH*32;

    floatx16 acc;
    #pragma unroll
    for (int r = 0; r < 16; ++r) acc[r] = 0.f;

    #pragma unroll
    for (int kh = 0; kh < 2; ++kh){         // 2 halves cap A-frag live range
      short8 av[4];
      #pragma unroll
      for (int i = 0; i < 4; ++i){
        const int kk = kh*4 + i;
        av[i] = *(const short8*)(ab + ((kk*2 + koct)*32 + l31)*8);
      }
      #pragma unroll
      for (int i = 0; i < 4; ++i){
        const int kk = kh*4 + i;
        // 8 distinct b128 addrs per wave (4 col x 2 koct), 8-way broadcast
        const uint32* tp = &T[cb][col*TSTRIDE + kk*16 + koct*8];
        const uint4v p0 = *(const uint4v*)(tp);
        const uint4v p1 = *(const uint4v*)(tp + 4);
        // mask BEFORE merge (r5's merged form OR-corrupted nibbles)
        uint4v bp;
        bp.x = ((p0.x >> sh) & 15u) | (((p0.y >> sh) & 15u) << 16) | 0x43004300u;
        bp.y = ((p0.z >> sh) & 15u) | (((p0.w >> sh) & 15u) << 16) | 0x43004300u;
        bp.z = ((p1.x >> sh) & 15u) | (((p1.y >> sh) & 15u) << 16) | 0x43004300u;
        bp.w = ((p1.z >> sh) & 15u) | (((p1.w >> sh) & 15u) << 16) | 0x43004300u;
        acc = __builtin_amdgcn_mfma_f32_32x32x16_bf16(
                  av[i], __builtin_bit_cast(short8, bp), acc, 0, 0, 0);
      }
    }
    // fold scale + this group's zero-point correction:
    //   accT += s*acc - s*(128+z)*S_g[row]
    const float t = sc[c] * (float)(128u + ((zc[c] >> sh) & 15u));
    const float* Sg = &g_S[(size_t)(ks*NCH + c)*M_DIM];
    float4v Sv[4];
    #pragma unroll
    for (int q = 0; q < 4; ++q)
      Sv[q] = *(const float4v*)(Sg + q*8 + 4*koct);  // rows q*8+4*koct+0..3
    #pragma unroll
    for (int r = 0; r < 16; ++r){
      accT[r] = fmaf(sc[c], acc[r], accT[r]);
      accT[r] = fmaf(-t, Sv[r >> 2][r & 3], accT[r]);
    }
    if (c + 1 < NCH) LDS_BARRIER();         // one non-draining barrier/chunk
  }
  // C/D layout (HW-verified m74/m101): col=lane&31, row=(r&3)+8*(r>>2)+4*koct
  #pragma unroll
  for (int r = 0; r < 16; ++r){
    const int row = (r & 3) + 8*(r >> 2) + 4*koct;
    atomicAdd(out + (size_t)row*N_DIM + n, accT[r]);
  }
}

extern "C" void kernel_launch(void* const* d_in, const int* in_sizes, int n_in,
                              void* d_out, int out_size, void* d_ws, size_t ws_size,
                              hipStream_t stream)
{
  const float*  x      = (const float*)d_in[0];
  const uint32* qw     = (const uint32*)d_in[1];
  const uint32* qz     = (const uint32*)d_in[2];
  const float*  scales = (const float*)d_in[3];
  const float*  bias   = (const float*)d_in[4];
  const float*  theta  = (const float*)d_in[5];
  const int*    pairs  = (const int*)d_in[6];
  const float*  cs     = (const float*)d_in[7];
  float* out = (float*)d_out;

  prep_kernel<<<dim3(512 + (N_DIM/256)*4), dim3(256), 0, stream>>>(
      x, theta, pairs, cs, bias, out);
  gemm_kernel<<<dim3(NB*KSPLIT), dim3(256), 0, stream>>>(qw, qz, scales, out);
}

// Round 8
// 222.276 us; speedup vs baseline: 1.0243x; 1.0243x over previous
//
#include <hip/hip_runtime.h>
#include <hip/hip_bf16.h>

using uint32   = unsigned int;
using ushort_t = unsigned short;
using short8   = __attribute__((ext_vector_type(8))) short;
using uint4v   = __attribute__((ext_vector_type(4))) uint32;
using float4v  = __attribute__((ext_vector_type(4))) float;
using floatx16 = __attribute__((ext_vector_type(16))) float;

#define M_DIM 32
#define K_DIM 8192
#define N_DIM 28672
#define QROW  (N_DIM/8)   /* 3584 dwords per qweight k-row */
#define KSPLIT 8          /* halved: atomics = KSPLIT*M*N scale with this */
#define BN    128
#define NB    (N_DIM/BN)  /* 224 n-blocks */
#define CH    128         /* k per chunk == QGS */
#define NCH   8           /* chunks per block (K_DIM / KSPLIT / CH) */
#define TCOLS (BN/8)      /* 16 dword-columns of T */
#define TSTRIDE 132       /* T column stride in dwords (128 + 4 pad) */

__device__ ushort_t g_xr2[M_DIM * K_DIM]; // rotated x, k-octet-major MFMA-A order
__device__ float    g_S[64 * M_DIM];      // per-group row sums of bf16(xr)

__device__ __forceinline__ float bf2f(ushort_t u){
  unsigned int v = ((unsigned int)u) << 16;
  return __builtin_bit_cast(float, v);
}
__device__ __forceinline__ ushort_t f2bf(float f){
  return __builtin_bit_cast(ushort_t, __float2bfloat16(f)); // RNE
}

// T4 barrier: LDS-visibility only. No vmcnt drain. Memory-clobber asm on
// both sides pins LDS-op code motion (rule #18).
#define LDS_BARRIER() do {                                   \
  asm volatile("s_waitcnt lgkmcnt(0)" ::: "memory");         \
  __builtin_amdgcn_s_barrier();                              \
  asm volatile("" ::: "memory");                             \
} while (0)

// ------------- prep: rotation + group sums, and bias broadcast ---------
// blocks [0,512): one 64-lane unit per (m,g) rotation.
// blocks [512,960): out[m][n] = bias[n] for 8 m-rows each.
__global__ __launch_bounds__(256) void prep_kernel(
    const float* __restrict__ x, const float* __restrict__ theta,
    const int* __restrict__ pairs, const float* __restrict__ cs,
    const float* __restrict__ bias, float* __restrict__ out)
{
  if (blockIdx.x >= 512){
    const int b  = blockIdx.x - 512;
    const int n  = (b % (N_DIM/256))*256 + threadIdx.x;
    const int m0 = (b / (N_DIM/256))*8;
    const float bv = bias[n];
    #pragma unroll
    for (int m = 0; m < 8; ++m) out[(size_t)(m0+m)*N_DIM + n] = bv;
    return;
  }
  __shared__ float xb[4][128];
  const int u    = threadIdx.x >> 6;
  const int lane = threadIdx.x & 63;
  const int id   = blockIdx.x * 4 + u;   // 0..2047 = m*64+g
  const int m    = id >> 6;
  const int g    = id & 63;
  const float* xp = x + m*K_DIM + g*128;
  int   ip[8], jp[8];
  float cv[8], sv[8];
  #pragma unroll
  for (int k = 0; k < 8; ++k){
    ip[k] = pairs[k*128 + 2*lane];
    jp[k] = pairs[k*128 + 2*lane + 1];
    const float th = theta[k*(K_DIM/2) + g*64 + lane];
    cv[k] = cosf(th); sv[k] = sinf(th);
  }
  xb[u][lane]    = xp[lane];
  xb[u][lane+64] = xp[lane+64];
  #pragma unroll
  for (int k = 0; k < 8; ++k){
    __syncthreads();
    const float xi = xb[u][ip[k]], xj = xb[u][jp[k]];
    xb[u][ip[k]] = cv[k]*xi - sv[k]*xj;
    xb[u][jp[k]] = sv[k]*xi + cv[k]*xj;
  }
  __syncthreads();
  const int base = g*128;
  const int k0 = base + lane, k1 = base + lane + 64;
  const ushort_t b0 = f2bf(xb[u][lane]    * cs[k0]);
  const ushort_t b1 = f2bf(xb[u][lane+64] * cs[k1]);
  g_xr2[(((size_t)(k0>>3))*32 + m)*8 + (k0&7)] = b0;
  g_xr2[(((size_t)(k1>>3))*32 + m)*8 + (k1&7)] = b1;
  float sum = bf2f(b0) + bf2f(b1);
  #pragma unroll
  for (int d = 32; d > 0; d >>= 1) sum += __shfl_xor(sum, d, 64);
  if (lane == 0) g_S[g*M_DIM + m] = sum;
}

// ---- GEMM: r7 structure, KSPLIT=8 (half the atomics), NCH=8 ----
// Rolling 4-deep B prefetch ring (static indices via full unroll).
// Everything else identical to round 7.
__global__ __launch_bounds__(256, 4) void gemm_kernel(
    const uint32* __restrict__ qw, const uint32* __restrict__ qz,
    const float* __restrict__ scales, float* __restrict__ out)
{
  __shared__ uint32 T[2][TCOLS*TSTRIDE];    // 2 x 8.4 KB transposed B chunk
  const int bid  = blockIdx.x;
  const int ks   = bid & (KSPLIT-1);
  const int nb   = bid >> 3;
  const int tid  = threadIdx.x;
  const int w    = tid >> 6;                // 0..3
  const int lane = tid & 63;
  const int l31  = lane & 31;
  const int koct = lane >> 5;
  const int n0   = nb * BN;
  const int n    = n0 + w*32 + l31;
  const uint32 sh = (uint32)((l31 & 7)*4);
  const int col  = w*4 + (l31 >> 3);        // T column 0..15 for this lane
  const int k0   = ks * (NCH*CH);           // 1024*ks

  // B global-load mapping: per chunk the panel is 128 rows x 16 dwords.
  // Lanes 0..3 cover 64 contiguous bytes of one k-row.
  const int brow = tid >> 2;                // 0..63
  const int bcq  = tid & 3;                 // 0..3
  const uint32* bbase = qw + (size_t)(k0 + brow)*QROW + (n0>>3) + bcq*4;
  const ushort_t* abase = g_xr2 + (size_t)k0*32;

  // ---- prelude: fill 4-deep B ring (chunks 0..3) ----
  uint4v bv0[4], bv1[4];
  #pragma unroll
  for (int c = 0; c < 4; ++c){
    const uint32* bb = bbase + (size_t)c*CH*QROW;
    bv0[c] = *(const uint4v*)(bb);
    bv1[c] = *(const uint4v*)(bb + (size_t)64*QROW);
  }

  float accT[16];
  #pragma unroll
  for (int r = 0; r < 16; ++r) accT[r] = 0.f;

  // write T[0] from slot 0; rotation mj=(j+bcq)&3 spreads write banks
  #pragma unroll
  for (int j = 0; j < 4; ++j){
    const int mj = (j + bcq) & 3;
    T[0][(bcq*4 + mj)*TSTRIDE + brow]      = bv0[0][mj];
    T[0][(bcq*4 + mj)*TSTRIDE + brow + 64] = bv1[0][mj];
  }
  { // slot 0 freed -> load chunk 4
    const uint32* bb = bbase + (size_t)4*CH*QROW;
    bv0[0] = *(const uint4v*)(bb);
    bv1[0] = *(const uint4v*)(bb + (size_t)64*QROW);
  }
  LDS_BARRIER();                            // T[0] visible

  #pragma unroll
  for (int c = 0; c < NCH; ++c){
    const int cb = c & 1, nx = cb ^ 1;
    // epilogue scalars for this chunk: issue early, use late
    const float  s  = scales[(size_t)(ks*NCH + c)*N_DIM + n];
    const uint32 zq = qz[(size_t)(ks*NCH + c)*QROW + (n>>3)];
    // T-write chunk c+1 from ring slot (c+1)&3, then refill it with c+5
    if (c + 1 < NCH){
      #pragma unroll
      for (int j = 0; j < 4; ++j){
        const int mj = (j + bcq) & 3;
        T[nx][(bcq*4 + mj)*TSTRIDE + brow]      = bv0[(c+1)&3][mj];
        T[nx][(bcq*4 + mj)*TSTRIDE + brow + 64] = bv1[(c+1)&3][mj];
      }
    }
    if (c + 5 < NCH){
      const uint32* bb = bbase + (size_t)(c+5)*CH*QROW;
      bv0[(c+1)&3] = *(const uint4v*)(bb);
      bv1[(c+1)&3] = *(const uint4v*)(bb + (size_t)64*QROW);
    }

    const ushort_t* ab = abase + (size_t)c*CH*32;

    floatx16 acc;
    #pragma unroll
    for (int r = 0; r < 16; ++r) acc[r] = 0.f;

    #pragma unroll
    for (int kh = 0; kh < 2; ++kh){         // 2 halves cap A-frag live range
      short8 av[4];
      #pragma unroll
      for (int i = 0; i < 4; ++i){
        const int kk = kh*4 + i;
        av[i] = *(const short8*)(ab + ((kk*2 + koct)*32 + l31)*8);
      }
      #pragma unroll
      for (int i = 0; i < 4; ++i){
        const int kk = kh*4 + i;
        // 8 distinct b128 addrs per wave (4 col x 2 koct), 8-way broadcast
        const uint32* tp = &T[cb][col*TSTRIDE + kk*16 + koct*8];
        const uint4v p0 = *(const uint4v*)(tp);
        const uint4v p1 = *(const uint4v*)(tp + 4);
        // mask BEFORE merge (r5's merged form OR-corrupted nibbles)
        uint4v bp;
        bp.x = ((p0.x >> sh) & 15u) | (((p0.y >> sh) & 15u) << 16) | 0x43004300u;
        bp.y = ((p0.z >> sh) & 15u) | (((p0.w >> sh) & 15u) << 16) | 0x43004300u;
        bp.z = ((p1.x >> sh) & 15u) | (((p1.y >> sh) & 15u) << 16) | 0x43004300u;
        bp.w = ((p1.z >> sh) & 15u) | (((p1.w >> sh) & 15u) << 16) | 0x43004300u;
        acc = __builtin_amdgcn_mfma_f32_32x32x16_bf16(
                  av[i], __builtin_bit_cast(short8, bp), acc, 0, 0, 0);
      }
    }
    // fold scale + this group's zero-point correction:
    //   accT += s*acc - s*(128+z)*S_g[row]
    const float t = s * (float)(128u + ((zq >> sh) & 15u));
    const float* Sg = &g_S[(size_t)(ks*NCH + c)*M_DIM];
    float4v Sv[4];
    #pragma unroll
    for (int q = 0; q < 4; ++q)
      Sv[q] = *(const float4v*)(Sg + q*8 + 4*koct);  // rows q*8+4*koct+0..3
    #pragma unroll
    for (int r = 0; r < 16; ++r){
      accT[r] = fmaf(s, acc[r], accT[r]);
      accT[r] = fmaf(-t, Sv[r >> 2][r & 3], accT[r]);
    }
    if (c + 1 < NCH) LDS_BARRIER();         // one non-draining barrier/chunk
  }
  // C/D layout (HW-verified m74/m101): col=lane&31, row=(r&3)+8*(r>>2)+4*koct
  #pragma unroll
  for (int r = 0; r < 16; ++r){
    const int row = (r & 3) + 8*(r >> 2) + 4*koct;
    atomicAdd(out + (size_t)row*N_DIM + n, accT[r]);
  }
}

extern "C" void kernel_launch(void* const* d_in, const int* in_sizes, int n_in,
                              void* d_out, int out_size, void* d_ws, size_t ws_size,
                              hipStream_t stream)
{
  const float*  x      = (const float*)d_in[0];
  const uint32* qw     = (const uint32*)d_in[1];
  const uint32* qz     = (const uint32*)d_in[2];
  const float*  scales = (const float*)d_in[3];
  const float*  bias   = (const float*)d_in[4];
  const float*  theta  = (const float*)d_in[5];
  const int*    pairs  = (const int*)d_in[6];
  const float*  cs     = (const float*)d_in[7];
  float* out = (float*)d_out;

  prep_kernel<<<dim3(512 + (N_DIM/256)*4), dim3(256), 0, stream>>>(
      x, theta, pairs, cs, bias, out);
  gemm_kernel<<<dim3(NB*KSPLIT), dim3(256), 0, stream>>>(qw, qz, scales, out);
}